// Round 1
// baseline (355.790 us; speedup 1.0000x reference)
//
#include <hip/hip_runtime.h>
#include <cstdint>
#include <cmath>

#define B_   8
#define L_   1024
#define DM_  256
#define DS_  16
#define DC_  4
#define DI_  512
#define DTR_ 16
#define M_   (B_*L_)    // 8192
#define NCH  32         // number of scan chunks
#define CH   32         // chunk length (NCH*CH == L_)

// ---------------------------------------------------------------------------
// Generic fp32 tiled GEMM: C[m,n] = act(sum_k A[m,k]*W(n,k) + bias[n])
//   BT=true : W is (N,K) row-major  -> W[n*K+k]   (einsum '...d,ed->...e')
//   BT=false: W is (K,N) row-major  -> W[k*N+n]   (plain @)
//   ACT: 0 none, 1 relu, 2 softplus
// Tiles: BM=64, BN=64, BK=16; 256 threads, 4x4 micro-tile per thread.
// M must be a multiple of 64; K a multiple of 16; N guarded.
// ---------------------------------------------------------------------------
template<bool BT, int ACT, bool BIAS>
__global__ __launch_bounds__(256)
void gemm_k(const float* __restrict__ A, int lda,
            const float* __restrict__ W, const float* __restrict__ bias,
            float* __restrict__ C, int ldc, int N, int K)
{
    __shared__ float As[16][65];
    __shared__ float Ws[16][65];
    const int tid = threadIdx.x;
    const int bm = blockIdx.x * 64;
    const int bn = blockIdx.y * 64;
    const int tm = (tid >> 4) << 2;   // 0..60
    const int tn = (tid & 15) << 2;   // 0..60
    const int ar = tid >> 2;          // 0..63
    const int ac = (tid & 3) << 2;    // 0,4,8,12

    float acc[4][4] = {};

    for (int k0 = 0; k0 < K; k0 += 16) {
        // A tile: 64 rows x 16 cols
        {
            const float4 av = *reinterpret_cast<const float4*>(
                A + (size_t)(bm + ar) * lda + k0 + ac);
            As[ac+0][ar] = av.x; As[ac+1][ar] = av.y;
            As[ac+2][ar] = av.z; As[ac+3][ar] = av.w;
        }
        if (BT) {
            float4 wv = make_float4(0.f, 0.f, 0.f, 0.f);
            if (bn + ar < N)
                wv = *reinterpret_cast<const float4*>(
                    W + (size_t)(bn + ar) * K + k0 + ac);
            Ws[ac+0][ar] = wv.x; Ws[ac+1][ar] = wv.y;
            Ws[ac+2][ar] = wv.z; Ws[ac+3][ar] = wv.w;
        } else {
            const int wr = tid >> 4;          // k-local 0..15
            const int wc = (tid & 15) << 2;   // n-local 0..60
            const float4 wv = *reinterpret_cast<const float4*>(
                W + (size_t)(k0 + wr) * N + bn + wc);
            Ws[wr][wc+0] = wv.x; Ws[wr][wc+1] = wv.y;
            Ws[wr][wc+2] = wv.z; Ws[wr][wc+3] = wv.w;
        }
        __syncthreads();
        #pragma unroll
        for (int kk = 0; kk < 16; kk++) {
            float a0 = As[kk][tm+0], a1 = As[kk][tm+1];
            float a2 = As[kk][tm+2], a3 = As[kk][tm+3];
            float b0 = Ws[kk][tn+0], b1 = Ws[kk][tn+1];
            float b2 = Ws[kk][tn+2], b3 = Ws[kk][tn+3];
            acc[0][0] += a0*b0; acc[0][1] += a0*b1; acc[0][2] += a0*b2; acc[0][3] += a0*b3;
            acc[1][0] += a1*b0; acc[1][1] += a1*b1; acc[1][2] += a1*b2; acc[1][3] += a1*b3;
            acc[2][0] += a2*b0; acc[2][1] += a2*b1; acc[2][2] += a2*b2; acc[2][3] += a2*b3;
            acc[3][0] += a3*b0; acc[3][1] += a3*b1; acc[3][2] += a3*b2; acc[3][3] += a3*b3;
        }
        __syncthreads();
    }

    #pragma unroll
    for (int i = 0; i < 4; i++) {
        #pragma unroll
        for (int j = 0; j < 4; j++) {
            const int n = bn + tn + j;
            if (n < N) {
                float v = acc[i][j];
                if (BIAS) v += bias[n];
                if (ACT == 1) v = fmaxf(v, 0.f);
                if (ACT == 2) v = (v > 20.f) ? v : log1pf(__expf(v));
                C[(size_t)(bm + tm + i) * ldc + n] = v;
            }
        }
    }
}

// ---------------------------------------------------------------------------
// Causal depthwise conv (DC=4 taps) + SiLU.  x lives in xz[:, 0:DI].
// ---------------------------------------------------------------------------
__global__ __launch_bounds__(256)
void conv_silu_k(const float* __restrict__ xz, const float* __restrict__ cw,
                 const float* __restrict__ cb, float* __restrict__ xs)
{
    const int gid = blockIdx.x * 256 + threadIdx.x;   // 0 .. M_*DI_-1
    const int d   = gid & (DI_ - 1);
    const int row = gid >> 9;          // b*L + t
    const int t   = row & (L_ - 1);
    float acc = cb[d];
    #pragma unroll
    for (int k = 0; k < DC_; k++) {
        const int tt = t - (DC_ - 1) + k;
        if (tt >= 0)
            acc += xz[(size_t)(row - (DC_ - 1) + k) * (2 * DI_) + d] * cw[d * DC_ + k];
    }
    xs[(size_t)row * DI_ + d] = acc * (1.f / (1.f + __expf(-acc)));
}

// ---------------------------------------------------------------------------
// Scan phase 1: per-chunk local recurrence from h=0; emits h_end and sum(dt).
// Block = (chunk c, batch b), thread = channel d. B-values staged in LDS.
// ---------------------------------------------------------------------------
__global__ __launch_bounds__(512)
void scan_phase1(const float* __restrict__ dt, const float* __restrict__ xs,
                 const float* __restrict__ xdbl, const float* __restrict__ A_log,
                 float* __restrict__ h_end, float* __restrict__ dtsum)
{
    const int c = blockIdx.x, b = blockIdx.y, d = threadIdx.x;
    __shared__ float Bs[CH][DS_];
    {
        const int tl = threadIdx.x >> 4, n = threadIdx.x & 15;
        Bs[tl][n] = xdbl[(size_t)(b * L_ + c * CH + tl) * 48 + 16 + n];
    }
    __syncthreads();
    float Av[DS_];
    #pragma unroll
    for (int n = 0; n < DS_; n++) Av[n] = -expf(A_log[d * DS_ + n]);
    float h[DS_] = {};
    float dts = 0.f;
    const int base = b * L_ + c * CH;
    for (int tl = 0; tl < CH; tl++) {
        const float dtv = dt[(size_t)(base + tl) * DI_ + d];
        const float xv  = xs[(size_t)(base + tl) * DI_ + d];
        dts += dtv;
        const float dtx = dtv * xv;
        #pragma unroll
        for (int n = 0; n < DS_; n++)
            h[n] = __expf(dtv * Av[n]) * h[n] + dtx * Bs[tl][n];
    }
    const size_t o = (size_t)(b * NCH + c) * DI_ + d;
    #pragma unroll
    for (int n = 0; n < DS_; n++) h_end[o * DS_ + n] = h[n];
    dtsum[o] = dts;
}

// ---------------------------------------------------------------------------
// Scan phase 2: sequential combine across chunks (thread = (b,d,n)).
// chunk transition factor = exp(A * sum_chunk dt)  (== prod of per-step dA).
// ---------------------------------------------------------------------------
__global__ __launch_bounds__(256)
void scan_phase2(const float* __restrict__ h_end, const float* __restrict__ dtsum,
                 const float* __restrict__ A_log, float* __restrict__ h_start)
{
    const int gid = blockIdx.x * 256 + threadIdx.x;   // B*DI*DS = 65536
    const int n = gid & 15;
    const int d = (gid >> 4) & (DI_ - 1);
    const int b = gid >> 13;
    const float Av = -expf(A_log[d * DS_ + n]);
    float hs = 0.f;
    for (int c = 0; c < NCH; c++) {
        const size_t o = (size_t)(b * NCH + c) * DI_ + d;
        h_start[o * DS_ + n] = hs;
        hs = __expf(Av * dtsum[o]) * hs + h_end[o * DS_ + n];
    }
}

// ---------------------------------------------------------------------------
// Scan phase 3: replay each chunk with incoming h_start, emit
// y = (sum_n h*C + x*D) * silu(z), written in-place over xs.
// ---------------------------------------------------------------------------
__global__ __launch_bounds__(512)
void scan_phase3(const float* __restrict__ dt, const float* __restrict__ xsy,
                 const float* __restrict__ xdbl, const float* __restrict__ A_log,
                 const float* __restrict__ Dv, const float* __restrict__ xz,
                 const float* __restrict__ h_start, float* __restrict__ yout)
{
    const int c = blockIdx.x, b = blockIdx.y, d = threadIdx.x;
    __shared__ float Bs[CH][DS_];
    __shared__ float Cs[CH][DS_];
    {
        const int tl = threadIdx.x >> 4, n = threadIdx.x & 15;
        const size_t r = (size_t)(b * L_ + c * CH + tl) * 48;
        Bs[tl][n] = xdbl[r + 16 + n];
        Cs[tl][n] = xdbl[r + 32 + n];
    }
    __syncthreads();
    float Av[DS_];
    #pragma unroll
    for (int n = 0; n < DS_; n++) Av[n] = -expf(A_log[d * DS_ + n]);
    float h[DS_];
    const size_t o = ((size_t)(b * NCH + c) * DI_ + d) * DS_;
    #pragma unroll
    for (int n = 0; n < DS_; n++) h[n] = h_start[o + n];
    const float Dd = Dv[d];
    const int base = b * L_ + c * CH;
    for (int tl = 0; tl < CH; tl++) {
        const size_t ro = (size_t)(base + tl);
        const float dtv = dt[ro * DI_ + d];
        const float xv  = xsy[ro * DI_ + d];
        const float dtx = dtv * xv;
        float acc = 0.f;
        #pragma unroll
        for (int n = 0; n < DS_; n++) {
            h[n] = __expf(dtv * Av[n]) * h[n] + dtx * Bs[tl][n];
            acc += h[n] * Cs[tl][n];
        }
        const float yv = acc + xv * Dd;
        const float zv = xz[ro * (2 * DI_) + DI_ + d];
        const float g  = zv * (1.f / (1.f + __expf(-zv)));
        yout[ro * DI_ + d] = yv * g;
    }
}

// ---------------------------------------------------------------------------
// Final N=1 GEMV: out[m] = h2[m,:] . w3 + b3
// ---------------------------------------------------------------------------
__global__ __launch_bounds__(256)
void final_dot(const float* __restrict__ h2, const float* __restrict__ w3,
               const float* __restrict__ b3, float* __restrict__ out)
{
    __shared__ float w3s[128];
    const int tid = threadIdx.x;
    if (tid < 128) w3s[tid] = w3[tid];
    __syncthreads();
    const int m = blockIdx.x * 256 + tid;
    float acc = b3[0];
    #pragma unroll 4
    for (int k = 0; k < 128; k++) acc += h2[(size_t)m * 128 + k] * w3s[k];
    out[m] = acc;
}

// ---------------------------------------------------------------------------
extern "C" void kernel_launch(void* const* d_in, const int* in_sizes, int n_in,
                              void* d_out, int out_size, void* d_ws, size_t ws_size,
                              hipStream_t stream)
{
    const float* state      = (const float*)d_in[0];
    const float* in_proj_w  = (const float*)d_in[1];
    const float* conv_w     = (const float*)d_in[2];
    const float* conv_b     = (const float*)d_in[3];
    const float* x_proj_w   = (const float*)d_in[4];
    const float* dt_proj_w  = (const float*)d_in[5];
    const float* dt_proj_b  = (const float*)d_in[6];
    const float* A_log      = (const float*)d_in[7];
    const float* Dp         = (const float*)d_in[8];
    const float* out_proj_w = (const float*)d_in[9];
    const float* w1 = (const float*)d_in[10];
    const float* b1 = (const float*)d_in[11];
    const float* w2 = (const float*)d_in[12];
    const float* b2 = (const float*)d_in[13];
    const float* w3 = (const float*)d_in[14];
    const float* b3 = (const float*)d_in[15];

    float* ws     = (float*)d_ws;
    float* xz     = ws;                                   // 8,388,608 f
    float* xs     = xz   + (size_t)M_ * 2 * DI_;          // 4,194,304 f
    float* xdbl   = xs   + (size_t)M_ * DI_;              //   393,216 f
    float* dt     = xdbl + (size_t)M_ * 48;               // 4,194,304 f
    float* h_end  = dt   + (size_t)M_ * DI_;              // 2,097,152 f
    float* dtsum  = h_end + (size_t)B_ * NCH * DI_ * DS_; //   131,072 f
    float* h_start = dtsum + (size_t)B_ * NCH * DI_;      // 2,097,152 f
    // tail buffers overlay xz (z consumed by phase3 before these are written)
    float* outb = xz;                // 2,097,152 f
    float* h1   = xz + 2097152;      // 2,097,152 f
    float* h2   = xz + 4194304;      // 1,048,576 f

    // 1. xz = state @ in_proj_w^T            (M=8192, N=1024, K=256)
    gemm_k<true, 0, false><<<dim3(M_/64, 1024/64), 256, 0, stream>>>(
        state, DM_, in_proj_w, nullptr, xz, 2*DI_, 2*DI_, DM_);
    // 2. causal conv + SiLU -> xs
    conv_silu_k<<<dim3(M_*DI_/256), 256, 0, stream>>>(xz, conv_w, conv_b, xs);
    // 3. x_dbl = xs @ x_proj_w^T             (N=48, K=512)
    gemm_k<true, 0, false><<<dim3(M_/64, 1), 256, 0, stream>>>(
        xs, DI_, x_proj_w, nullptr, xdbl, 48, 48, DI_);
    // 4. dt = softplus(dtr @ dt_proj_w^T + b)  (A = x_dbl[:, :16], N=512, K=16)
    gemm_k<true, 2, true><<<dim3(M_/64, DI_/64), 256, 0, stream>>>(
        xdbl, 48, dt_proj_w, dt_proj_b, dt, DI_, DI_, DTR_);
    // 5-7. chunked selective scan
    scan_phase1<<<dim3(NCH, B_), 512, 0, stream>>>(dt, xs, xdbl, A_log, h_end, dtsum);
    scan_phase2<<<dim3(256), 256, 0, stream>>>(h_end, dtsum, A_log, h_start);
    scan_phase3<<<dim3(NCH, B_), 512, 0, stream>>>(dt, xs, xdbl, A_log, Dp, xz, h_start, xs);
    // 8. out = y @ out_proj_w^T              (N=256, K=512), y lives in xs
    gemm_k<true, 0, false><<<dim3(M_/64, DM_/64), 256, 0, stream>>>(
        xs, DI_, out_proj_w, nullptr, outb, DM_, DM_, DI_);
    // 9. h1 = relu(out @ w1 + b1)            (N=256, K=256)
    gemm_k<false, 1, true><<<dim3(M_/64, 256/64), 256, 0, stream>>>(
        outb, DM_, w1, b1, h1, 256, 256, 256);
    // 10. h2 = relu(h1 @ w2 + b2)            (N=128, K=256)
    gemm_k<false, 1, true><<<dim3(M_/64, 128/64), 256, 0, stream>>>(
        h1, 256, w2, b2, h2, 128, 128, 256);
    // 11. out = h2 @ w3 + b3                 (N=1)
    final_dot<<<dim3(M_/256), 256, 0, stream>>>(h2, w3, b3, (float*)d_out);
}

// Round 2
// 212.858 us; speedup vs baseline: 1.6715x; 1.6715x over previous
//
#include <hip/hip_runtime.h>
#include <cstdint>
#include <cmath>

#define B_   8
#define L_   1024
#define DM_  256
#define DS_  16
#define DC_  4
#define DI_  512
#define DTR_ 16
#define M_   (B_*L_)    // 8192
#define NCH  32         // number of scan chunks
#define CH   32         // chunk length (NCH*CH == L_)

using half8 = __attribute__((ext_vector_type(8))) _Float16;
using half4 = __attribute__((ext_vector_type(4))) _Float16;
using f32x4 = __attribute__((ext_vector_type(4))) float;

// ---------------------------------------------------------------------------
// fp16 MFMA GEMM: C[m,n] = act(sum_k A[m,k]*W[n,k] + bias[n])
// A: (M,K) fp16 row-major, W: (N,K) fp16 row-major, C: fp32 or fp16.
// Tile BM=128, BN=64, BK=32; 256 threads = 4 waves; wave tile 64x32
// (4x2 fragments of 16x16, one mfma_f32_16x16x32_f16 each per K-step).
// Grid must cover M,N exactly (M%128==0, N%64==0, K%32==0).
// LDS rows padded to 40 halfs (80B stride -> 2-way read conflicts = free).
// ---------------------------------------------------------------------------
template<int ACT, bool BIAS, bool OUTH>
__global__ __launch_bounds__(256)
void hgemm_k(const _Float16* __restrict__ A, int lda,
             const _Float16* __restrict__ W,
             const float* __restrict__ bias,
             void* __restrict__ Cv, int ldc, int K)
{
    __shared__ _Float16 Ash[128][40];
    __shared__ _Float16 Bsh[64][40];
    const int tid  = threadIdx.x;
    const int lane = tid & 63;
    const int w    = tid >> 6;
    const int wm   = (w >> 1) * 64;
    const int wn   = (w & 1) * 32;
    const int bm   = blockIdx.x * 128;
    const int bn   = blockIdx.y * 64;

    const int fr = lane & 15;          // fragment row/col
    const int fk = (lane >> 4) * 8;    // fragment k offset

    // staging map: 8 halfs (16B) per load
    const int sr = tid >> 2;           // 0..63
    const int sg = (tid & 3) * 8;      // 0,8,16,24

    f32x4 acc[4][2] = {};

    for (int k0 = 0; k0 < K; k0 += 32) {
        // A tile: rows sr and sr+64
        *reinterpret_cast<half8*>(&Ash[sr][sg]) =
            *reinterpret_cast<const half8*>(A + (size_t)(bm + sr) * lda + k0 + sg);
        *reinterpret_cast<half8*>(&Ash[sr + 64][sg]) =
            *reinterpret_cast<const half8*>(A + (size_t)(bm + sr + 64) * lda + k0 + sg);
        // B tile
        *reinterpret_cast<half8*>(&Bsh[sr][sg]) =
            *reinterpret_cast<const half8*>(W + (size_t)(bn + sr) * K + k0 + sg);
        __syncthreads();

        half8 af[4], bf[2];
        #pragma unroll
        for (int mf = 0; mf < 4; mf++)
            af[mf] = *reinterpret_cast<const half8*>(&Ash[wm + mf * 16 + fr][fk]);
        #pragma unroll
        for (int nf = 0; nf < 2; nf++)
            bf[nf] = *reinterpret_cast<const half8*>(&Bsh[wn + nf * 16 + fr][fk]);
        #pragma unroll
        for (int mf = 0; mf < 4; mf++)
            #pragma unroll
            for (int nf = 0; nf < 2; nf++)
                acc[mf][nf] = __builtin_amdgcn_mfma_f32_16x16x32_f16(
                    af[mf], bf[nf], acc[mf][nf], 0, 0, 0);
        __syncthreads();
    }

    // epilogue: D row = (lane>>4)*4 + r, col = lane&15
    const int orow = (lane >> 4) * 4;
    const int ocol = lane & 15;
    #pragma unroll
    for (int mf = 0; mf < 4; mf++) {
        #pragma unroll
        for (int nf = 0; nf < 2; nf++) {
            const int gc = bn + wn + nf * 16 + ocol;
            float b = BIAS ? bias[gc] : 0.f;
            #pragma unroll
            for (int r = 0; r < 4; r++) {
                const int gr = bm + wm + mf * 16 + orow + r;
                float v = acc[mf][nf][r] + b;
                if (ACT == 1) v = fmaxf(v, 0.f);
                if (OUTH)
                    ((_Float16*)Cv)[(size_t)gr * ldc + gc] = (_Float16)v;
                else
                    ((float*)Cv)[(size_t)gr * ldc + gc] = v;
            }
        }
    }
}

// ---------------------------------------------------------------------------
// fp32 tiled GEMM (kept for small N / small K cases: x_proj, dt)
// ---------------------------------------------------------------------------
template<int ACT, bool BIAS>
__global__ __launch_bounds__(256)
void gemm_k(const float* __restrict__ A, int lda,
            const float* __restrict__ W, const float* __restrict__ bias,
            float* __restrict__ C, int ldc, int N, int K)
{
    __shared__ float As[16][65];
    __shared__ float Ws[16][65];
    const int tid = threadIdx.x;
    const int bm = blockIdx.x * 64;
    const int bn = blockIdx.y * 64;
    const int tm = (tid >> 4) << 2;
    const int tn = (tid & 15) << 2;
    const int ar = tid >> 2;
    const int ac = (tid & 3) << 2;

    float acc[4][4] = {};

    for (int k0 = 0; k0 < K; k0 += 16) {
        {
            const float4 av = *reinterpret_cast<const float4*>(
                A + (size_t)(bm + ar) * lda + k0 + ac);
            As[ac+0][ar] = av.x; As[ac+1][ar] = av.y;
            As[ac+2][ar] = av.z; As[ac+3][ar] = av.w;
        }
        {
            float4 wv = make_float4(0.f, 0.f, 0.f, 0.f);
            if (bn + ar < N)
                wv = *reinterpret_cast<const float4*>(
                    W + (size_t)(bn + ar) * K + k0 + ac);
            Ws[ac+0][ar] = wv.x; Ws[ac+1][ar] = wv.y;
            Ws[ac+2][ar] = wv.z; Ws[ac+3][ar] = wv.w;
        }
        __syncthreads();
        #pragma unroll
        for (int kk = 0; kk < 16; kk++) {
            float a0 = As[kk][tm+0], a1 = As[kk][tm+1];
            float a2 = As[kk][tm+2], a3 = As[kk][tm+3];
            float b0 = Ws[kk][tn+0], b1 = Ws[kk][tn+1];
            float b2 = Ws[kk][tn+2], b3 = Ws[kk][tn+3];
            acc[0][0] += a0*b0; acc[0][1] += a0*b1; acc[0][2] += a0*b2; acc[0][3] += a0*b3;
            acc[1][0] += a1*b0; acc[1][1] += a1*b1; acc[1][2] += a1*b2; acc[1][3] += a1*b3;
            acc[2][0] += a2*b0; acc[2][1] += a2*b1; acc[2][2] += a2*b2; acc[2][3] += a2*b3;
            acc[3][0] += a3*b0; acc[3][1] += a3*b1; acc[3][2] += a3*b2; acc[3][3] += a3*b3;
        }
        __syncthreads();
    }

    #pragma unroll
    for (int i = 0; i < 4; i++) {
        #pragma unroll
        for (int j = 0; j < 4; j++) {
            const int n = bn + tn + j;
            if (n < N) {
                float v = acc[i][j];
                if (BIAS) v += bias[n];
                if (ACT == 1) v = fmaxf(v, 0.f);
                if (ACT == 2) v = (v > 20.f) ? v : log1pf(__expf(v));
                C[(size_t)(bm + tm + i) * ldc + n] = v;
            }
        }
    }
}

// ---------------------------------------------------------------------------
// fp32 -> fp16 converters (weights/state prep)
// ---------------------------------------------------------------------------
__global__ __launch_bounds__(256)
void cvt_f2h(const float* __restrict__ in, _Float16* __restrict__ out, int n4)
{
    const int g = blockIdx.x * 256 + threadIdx.x;
    if (g < n4) {
        const float4 v = reinterpret_cast<const float4*>(in)[g];
        half4 h;
        h[0] = (_Float16)v.x; h[1] = (_Float16)v.y;
        h[2] = (_Float16)v.z; h[3] = (_Float16)v.w;
        reinterpret_cast<half4*>(out)[g] = h;
    }
}

// in: (R,C) row-major -> out: (C,R) row-major (transpose + convert)
__global__ __launch_bounds__(256)
void cvtT_f2h(const float* __restrict__ in, _Float16* __restrict__ out, int R, int C)
{
    const int g = blockIdx.x * 256 + threadIdx.x;
    if (g < R * C) {
        const int r = g / C, c = g - r * C;
        out[(size_t)c * R + r] = (_Float16)in[g];
    }
}

// ---------------------------------------------------------------------------
// Causal depthwise conv (DC=4 taps) + SiLU.  x lives in xz[:, 0:DI].
// ---------------------------------------------------------------------------
__global__ __launch_bounds__(256)
void conv_silu_k(const float* __restrict__ xz, const float* __restrict__ cw,
                 const float* __restrict__ cb, float* __restrict__ xs)
{
    const int gid = blockIdx.x * 256 + threadIdx.x;
    const int d   = gid & (DI_ - 1);
    const int row = gid >> 9;
    const int t   = row & (L_ - 1);
    float acc = cb[d];
    #pragma unroll
    for (int k = 0; k < DC_; k++) {
        const int tt = t - (DC_ - 1) + k;
        if (tt >= 0)
            acc += xz[(size_t)(row - (DC_ - 1) + k) * (2 * DI_) + d] * cw[d * DC_ + k];
    }
    xs[(size_t)row * DI_ + d] = acc * (1.f / (1.f + __expf(-acc)));
}

// ---------------------------------------------------------------------------
// Scan phase 1
// ---------------------------------------------------------------------------
__global__ __launch_bounds__(512)
void scan_phase1(const float* __restrict__ dt, const float* __restrict__ xs,
                 const float* __restrict__ xdbl, const float* __restrict__ A_log,
                 float* __restrict__ h_end, float* __restrict__ dtsum)
{
    const int c = blockIdx.x, b = blockIdx.y, d = threadIdx.x;
    __shared__ float Bs[CH][DS_];
    {
        const int tl = threadIdx.x >> 4, n = threadIdx.x & 15;
        Bs[tl][n] = xdbl[(size_t)(b * L_ + c * CH + tl) * 48 + 16 + n];
    }
    __syncthreads();
    float Av[DS_];
    #pragma unroll
    for (int n = 0; n < DS_; n++) Av[n] = -expf(A_log[d * DS_ + n]);
    float h[DS_] = {};
    float dts = 0.f;
    const int base = b * L_ + c * CH;
    for (int tl = 0; tl < CH; tl++) {
        const float dtv = dt[(size_t)(base + tl) * DI_ + d];
        const float xv  = xs[(size_t)(base + tl) * DI_ + d];
        dts += dtv;
        const float dtx = dtv * xv;
        #pragma unroll
        for (int n = 0; n < DS_; n++)
            h[n] = __expf(dtv * Av[n]) * h[n] + dtx * Bs[tl][n];
    }
    const size_t o = (size_t)(b * NCH + c) * DI_ + d;
    #pragma unroll
    for (int n = 0; n < DS_; n++) h_end[o * DS_ + n] = h[n];
    dtsum[o] = dts;
}

// ---------------------------------------------------------------------------
// Scan phase 2
// ---------------------------------------------------------------------------
__global__ __launch_bounds__(256)
void scan_phase2(const float* __restrict__ h_end, const float* __restrict__ dtsum,
                 const float* __restrict__ A_log, float* __restrict__ h_start)
{
    const int gid = blockIdx.x * 256 + threadIdx.x;
    const int n = gid & 15;
    const int d = (gid >> 4) & (DI_ - 1);
    const int b = gid >> 13;
    const float Av = -expf(A_log[d * DS_ + n]);
    float hs = 0.f;
    for (int c = 0; c < NCH; c++) {
        const size_t o = (size_t)(b * NCH + c) * DI_ + d;
        h_start[o * DS_ + n] = hs;
        hs = __expf(Av * dtsum[o]) * hs + h_end[o * DS_ + n];
    }
}

// ---------------------------------------------------------------------------
// Scan phase 3 -> y written as fp16 (input of out_proj hgemm)
// ---------------------------------------------------------------------------
__global__ __launch_bounds__(512)
void scan_phase3(const float* __restrict__ dt, const float* __restrict__ xsy,
                 const float* __restrict__ xdbl, const float* __restrict__ A_log,
                 const float* __restrict__ Dv, const float* __restrict__ xz,
                 const float* __restrict__ h_start, _Float16* __restrict__ yout)
{
    const int c = blockIdx.x, b = blockIdx.y, d = threadIdx.x;
    __shared__ float Bs[CH][DS_];
    __shared__ float Cs[CH][DS_];
    {
        const int tl = threadIdx.x >> 4, n = threadIdx.x & 15;
        const size_t r = (size_t)(b * L_ + c * CH + tl) * 48;
        Bs[tl][n] = xdbl[r + 16 + n];
        Cs[tl][n] = xdbl[r + 32 + n];
    }
    __syncthreads();
    float Av[DS_];
    #pragma unroll
    for (int n = 0; n < DS_; n++) Av[n] = -expf(A_log[d * DS_ + n]);
    float h[DS_];
    const size_t o = ((size_t)(b * NCH + c) * DI_ + d) * DS_;
    #pragma unroll
    for (int n = 0; n < DS_; n++) h[n] = h_start[o + n];
    const float Dd = Dv[d];
    const int base = b * L_ + c * CH;
    for (int tl = 0; tl < CH; tl++) {
        const size_t ro = (size_t)(base + tl);
        const float dtv = dt[ro * DI_ + d];
        const float xv  = xsy[ro * DI_ + d];
        const float dtx = dtv * xv;
        float acc = 0.f;
        #pragma unroll
        for (int n = 0; n < DS_; n++) {
            h[n] = __expf(dtv * Av[n]) * h[n] + dtx * Bs[tl][n];
            acc += h[n] * Cs[tl][n];
        }
        const float yv = acc + xv * Dd;
        const float zv = xz[ro * (2 * DI_) + DI_ + d];
        const float g  = zv * (1.f / (1.f + __expf(-zv)));
        yout[ro * DI_ + d] = (_Float16)(yv * g);
    }
}

// ---------------------------------------------------------------------------
// Final N=1 GEMV
// ---------------------------------------------------------------------------
__global__ __launch_bounds__(256)
void final_dot(const float* __restrict__ h2, const float* __restrict__ w3,
               const float* __restrict__ b3, float* __restrict__ out)
{
    __shared__ float w3s[128];
    const int tid = threadIdx.x;
    if (tid < 128) w3s[tid] = w3[tid];
    __syncthreads();
    const int m = blockIdx.x * 256 + tid;
    float acc = b3[0];
    #pragma unroll 4
    for (int k = 0; k < 128; k++) acc += h2[(size_t)m * 128 + k] * w3s[k];
    out[m] = acc;
}

// ---------------------------------------------------------------------------
extern "C" void kernel_launch(void* const* d_in, const int* in_sizes, int n_in,
                              void* d_out, int out_size, void* d_ws, size_t ws_size,
                              hipStream_t stream)
{
    const float* state      = (const float*)d_in[0];
    const float* in_proj_w  = (const float*)d_in[1];
    const float* conv_w     = (const float*)d_in[2];
    const float* conv_b     = (const float*)d_in[3];
    const float* x_proj_w   = (const float*)d_in[4];
    const float* dt_proj_w  = (const float*)d_in[5];
    const float* dt_proj_b  = (const float*)d_in[6];
    const float* A_log      = (const float*)d_in[7];
    const float* Dp         = (const float*)d_in[8];
    const float* out_proj_w = (const float*)d_in[9];
    const float* w1 = (const float*)d_in[10];
    const float* b1 = (const float*)d_in[11];
    const float* w2 = (const float*)d_in[12];
    const float* b2 = (const float*)d_in[13];
    const float* w3 = (const float*)d_in[14];
    const float* b3 = (const float*)d_in[15];

    float* ws      = (float*)d_ws;
    float* xz      = ws;                                   // 8,388,608 f
    float* xs      = xz     + (size_t)M_ * 2 * DI_;        // 4,194,304 f
    float* xdbl    = xs     + (size_t)M_ * DI_;            //   393,216 f
    float* dt      = xdbl   + (size_t)M_ * 48;             // 4,194,304 f
    float* h_end   = dt     + (size_t)M_ * DI_;            // 2,097,152 f
    float* dtsum   = h_end  + (size_t)B_ * NCH * DI_ * DS_;//   131,072 f
    float* h_start = dtsum  + (size_t)B_ * NCH * DI_;      // 2,097,152 f
    _Float16* y_h  = (_Float16*)(h_start + 2097152);       // 2,097,152 h (1,048,576 f)
    _Float16* st_h = y_h + 2097152;                        // 2,097,152 h
    _Float16* wih  = st_h + 2097152;                       //   262,144 h
    _Float16* woh  = wih + 262144;                         //   131,072 h
    _Float16* w1t  = woh + 131072;                         //    65,536 h
    _Float16* w2t  = w1t + 65536;                          //    32,768 h
    // tail buffers overlay xz (z is consumed by phase3 before these are written)
    _Float16* outb_h = (_Float16*)xz;                      // 2,097,152 h
    _Float16* h1_h   = (_Float16*)(xz + 1048576);          // 2,097,152 h
    float*    h2     = xz + 2097152;                       // 1,048,576 f

    // 0. fp16 prep: state + weights
    cvt_f2h<<<dim3(2048), 256, 0, stream>>>(state, st_h, M_ * DM_ / 4);
    cvt_f2h<<<dim3(256),  256, 0, stream>>>(in_proj_w, wih, 2 * DI_ * DM_ / 4);
    cvt_f2h<<<dim3(128),  256, 0, stream>>>(out_proj_w, woh, DM_ * DI_ / 4);
    cvtT_f2h<<<dim3(256), 256, 0, stream>>>(w1, w1t, 256, 256);
    cvtT_f2h<<<dim3(128), 256, 0, stream>>>(w2, w2t, 256, 128);

    // 1. xz = state @ in_proj_w^T            (M=8192, N=1024, K=256)
    hgemm_k<0, false, false><<<dim3(M_/128, 1024/64), 256, 0, stream>>>(
        st_h, DM_, wih, nullptr, xz, 2*DI_, DM_);
    // 2. causal conv + SiLU -> xs
    conv_silu_k<<<dim3(M_*DI_/256), 256, 0, stream>>>(xz, conv_w, conv_b, xs);
    // 3. x_dbl = xs @ x_proj_w^T             (N=48, K=512) fp32
    gemm_k<0, false><<<dim3(M_/64, 1), 256, 0, stream>>>(
        xs, DI_, x_proj_w, nullptr, xdbl, 48, 48, DI_);
    // 4. dt = softplus(dtr @ dt_proj_w^T + b)  (N=512, K=16) fp32
    gemm_k<2, true><<<dim3(M_/64, DI_/64), 256, 0, stream>>>(
        xdbl, 48, dt_proj_w, dt_proj_b, dt, DI_, DI_, DTR_);
    // 5-7. chunked selective scan
    scan_phase1<<<dim3(NCH, B_), 512, 0, stream>>>(dt, xs, xdbl, A_log, h_end, dtsum);
    scan_phase2<<<dim3(256), 256, 0, stream>>>(h_end, dtsum, A_log, h_start);
    scan_phase3<<<dim3(NCH, B_), 512, 0, stream>>>(dt, xs, xdbl, A_log, Dp, xz, h_start, y_h);
    // 8. out = y @ out_proj_w^T              (N=256, K=512) -> fp16
    hgemm_k<0, false, true><<<dim3(M_/128, DM_/64), 256, 0, stream>>>(
        y_h, DI_, woh, nullptr, outb_h, DM_, DI_);
    // 9. h1 = relu(out @ w1 + b1)            (N=256, K=256) -> fp16
    hgemm_k<1, true, true><<<dim3(M_/128, 256/64), 256, 0, stream>>>(
        outb_h, DM_, w1t, b1, h1_h, 256, 256);
    // 10. h2 = relu(h1 @ w2 + b2)            (N=128, K=256) -> fp32
    hgemm_k<1, true, false><<<dim3(M_/128, 128/64), 256, 0, stream>>>(
        h1_h, 256, w2t, b2, h2, 128, 256);
    // 11. out = h2 @ w3 + b3                 (N=1)
    final_dot<<<dim3(M_/256), 256, 0, stream>>>(h2, w3, b3, (float*)d_out);
}

// Round 3
// 181.980 us; speedup vs baseline: 1.9551x; 1.1697x over previous
//
#include <hip/hip_runtime.h>
#include <cstdint>
#include <cmath>

#define B_   8
#define L_   1024
#define DM_  256
#define DS_  16
#define DC_  4
#define DI_  512
#define DTR_ 16
#define M_   (B_*L_)    // 8192
#define NCH  32         // number of scan chunks
#define CH   32         // chunk length (NCH*CH == L_)

using half8 = __attribute__((ext_vector_type(8))) _Float16;
using half4 = __attribute__((ext_vector_type(4))) _Float16;
using f32x4 = __attribute__((ext_vector_type(4))) float;

// ---------------------------------------------------------------------------
// fp16 MFMA GEMM: C[m,n] = act(sum_k A[m,k]*W[n,k] + bias[n])
// Tile BM=128, BN=64, BK=32; 256 threads = 4 waves; wave tile 64x32.
// ---------------------------------------------------------------------------
template<int ACT, bool BIAS, bool OUTH>
__global__ __launch_bounds__(256)
void hgemm_k(const _Float16* __restrict__ A, int lda,
             const _Float16* __restrict__ W,
             const float* __restrict__ bias,
             void* __restrict__ Cv, int ldc, int K)
{
    __shared__ _Float16 Ash[128][40];
    __shared__ _Float16 Bsh[64][40];
    const int tid  = threadIdx.x;
    const int lane = tid & 63;
    const int w    = tid >> 6;
    const int wm   = (w >> 1) * 64;
    const int wn   = (w & 1) * 32;
    const int bm   = blockIdx.x * 128;
    const int bn   = blockIdx.y * 64;

    const int fr = lane & 15;
    const int fk = (lane >> 4) * 8;
    const int sr = tid >> 2;
    const int sg = (tid & 3) * 8;

    f32x4 acc[4][2] = {};

    for (int k0 = 0; k0 < K; k0 += 32) {
        *reinterpret_cast<half8*>(&Ash[sr][sg]) =
            *reinterpret_cast<const half8*>(A + (size_t)(bm + sr) * lda + k0 + sg);
        *reinterpret_cast<half8*>(&Ash[sr + 64][sg]) =
            *reinterpret_cast<const half8*>(A + (size_t)(bm + sr + 64) * lda + k0 + sg);
        *reinterpret_cast<half8*>(&Bsh[sr][sg]) =
            *reinterpret_cast<const half8*>(W + (size_t)(bn + sr) * K + k0 + sg);
        __syncthreads();

        half8 af[4], bf[2];
        #pragma unroll
        for (int mf = 0; mf < 4; mf++)
            af[mf] = *reinterpret_cast<const half8*>(&Ash[wm + mf * 16 + fr][fk]);
        #pragma unroll
        for (int nf = 0; nf < 2; nf++)
            bf[nf] = *reinterpret_cast<const half8*>(&Bsh[wn + nf * 16 + fr][fk]);
        #pragma unroll
        for (int mf = 0; mf < 4; mf++)
            #pragma unroll
            for (int nf = 0; nf < 2; nf++)
                acc[mf][nf] = __builtin_amdgcn_mfma_f32_16x16x32_f16(
                    af[mf], bf[nf], acc[mf][nf], 0, 0, 0);
        __syncthreads();
    }

    const int orow = (lane >> 4) * 4;
    const int ocol = lane & 15;
    #pragma unroll
    for (int mf = 0; mf < 4; mf++) {
        #pragma unroll
        for (int nf = 0; nf < 2; nf++) {
            const int gc = bn + wn + nf * 16 + ocol;
            float b = BIAS ? bias[gc] : 0.f;
            #pragma unroll
            for (int r = 0; r < 4; r++) {
                const int gr = bm + wm + mf * 16 + orow + r;
                float v = acc[mf][nf][r] + b;
                if (ACT == 1) v = fmaxf(v, 0.f);
                if (OUTH)
                    ((_Float16*)Cv)[(size_t)gr * ldc + gc] = (_Float16)v;
                else
                    ((float*)Cv)[(size_t)gr * ldc + gc] = v;
            }
        }
    }
}

// ---------------------------------------------------------------------------
// x_proj MFMA kernel: xs (M,512) fp32 -> x_dbl (M,48), split outputs.
// BM=64, BN=48 (3 fragments), BK=32; 4 waves x (16 rows x 48 cols).
// fp32->fp16 conversion fused into LDS staging.
// cols 0..15 -> dtr32 (M,16) fp32 ; cols 16..47 -> xdbl32 (M,32) fp32 (B,C)
// ---------------------------------------------------------------------------
__global__ __launch_bounds__(256)
void xproj_k(const float* __restrict__ xs,
             const float* __restrict__ xpw,
             float* __restrict__ dtr32,
             float* __restrict__ xdbl32)
{
    __shared__ _Float16 Ash[64][40];
    __shared__ _Float16 Bsh[48][40];
    const int tid  = threadIdx.x;
    const int lane = tid & 63;
    const int w    = tid >> 6;
    const int bm   = blockIdx.x * 64;
    const int fr   = lane & 15;
    const int fk   = (lane >> 4) * 8;
    const int sr   = tid >> 2;
    const int sg   = (tid & 3) * 8;

    f32x4 acc[3] = {};

    for (int k0 = 0; k0 < 512; k0 += 32) {
        {
            const float4 a0 = *reinterpret_cast<const float4*>(
                xs + (size_t)(bm + sr) * 512 + k0 + sg);
            const float4 a1 = *reinterpret_cast<const float4*>(
                xs + (size_t)(bm + sr) * 512 + k0 + sg + 4);
            half8 hv;
            hv[0] = (_Float16)a0.x; hv[1] = (_Float16)a0.y;
            hv[2] = (_Float16)a0.z; hv[3] = (_Float16)a0.w;
            hv[4] = (_Float16)a1.x; hv[5] = (_Float16)a1.y;
            hv[6] = (_Float16)a1.z; hv[7] = (_Float16)a1.w;
            *reinterpret_cast<half8*>(&Ash[sr][sg]) = hv;
        }
        if (sr < 48) {
            const float4 b0 = *reinterpret_cast<const float4*>(
                xpw + (size_t)sr * 512 + k0 + sg);
            const float4 b1 = *reinterpret_cast<const float4*>(
                xpw + (size_t)sr * 512 + k0 + sg + 4);
            half8 hv;
            hv[0] = (_Float16)b0.x; hv[1] = (_Float16)b0.y;
            hv[2] = (_Float16)b0.z; hv[3] = (_Float16)b0.w;
            hv[4] = (_Float16)b1.x; hv[5] = (_Float16)b1.y;
            hv[6] = (_Float16)b1.z; hv[7] = (_Float16)b1.w;
            *reinterpret_cast<half8*>(&Bsh[sr][sg]) = hv;
        }
        __syncthreads();
        const half8 af = *reinterpret_cast<const half8*>(&Ash[w * 16 + fr][fk]);
        #pragma unroll
        for (int nf = 0; nf < 3; nf++) {
            const half8 bf = *reinterpret_cast<const half8*>(&Bsh[nf * 16 + fr][fk]);
            acc[nf] = __builtin_amdgcn_mfma_f32_16x16x32_f16(af, bf, acc[nf], 0, 0, 0);
        }
        __syncthreads();
    }

    const int orow = (lane >> 4) * 4;
    const int ocol = lane & 15;
    #pragma unroll
    for (int nf = 0; nf < 3; nf++) {
        #pragma unroll
        for (int r = 0; r < 4; r++) {
            const int gr = bm + w * 16 + orow + r;
            const float v = acc[nf][r];
            if (nf == 0)
                dtr32[(size_t)gr * 16 + ocol] = v;
            else
                xdbl32[(size_t)gr * 32 + (nf - 1) * 16 + ocol] = v;
        }
    }
}

// ---------------------------------------------------------------------------
// fp32 tiled GEMM (kept for dt: N=512, K=16)
// ---------------------------------------------------------------------------
template<int ACT, bool BIAS>
__global__ __launch_bounds__(256)
void gemm_k(const float* __restrict__ A, int lda,
            const float* __restrict__ W, const float* __restrict__ bias,
            float* __restrict__ C, int ldc, int N, int K)
{
    __shared__ float As[16][65];
    __shared__ float Ws[16][65];
    const int tid = threadIdx.x;
    const int bm = blockIdx.x * 64;
    const int bn = blockIdx.y * 64;
    const int tm = (tid >> 4) << 2;
    const int tn = (tid & 15) << 2;
    const int ar = tid >> 2;
    const int ac = (tid & 3) << 2;

    float acc[4][4] = {};

    for (int k0 = 0; k0 < K; k0 += 16) {
        {
            const float4 av = *reinterpret_cast<const float4*>(
                A + (size_t)(bm + ar) * lda + k0 + ac);
            As[ac+0][ar] = av.x; As[ac+1][ar] = av.y;
            As[ac+2][ar] = av.z; As[ac+3][ar] = av.w;
        }
        {
            float4 wv = make_float4(0.f, 0.f, 0.f, 0.f);
            if (bn + ar < N)
                wv = *reinterpret_cast<const float4*>(
                    W + (size_t)(bn + ar) * K + k0 + ac);
            Ws[ac+0][ar] = wv.x; Ws[ac+1][ar] = wv.y;
            Ws[ac+2][ar] = wv.z; Ws[ac+3][ar] = wv.w;
        }
        __syncthreads();
        #pragma unroll
        for (int kk = 0; kk < 16; kk++) {
            float a0 = As[kk][tm+0], a1 = As[kk][tm+1];
            float a2 = As[kk][tm+2], a3 = As[kk][tm+3];
            float b0 = Ws[kk][tn+0], b1 = Ws[kk][tn+1];
            float b2 = Ws[kk][tn+2], b3 = Ws[kk][tn+3];
            acc[0][0] += a0*b0; acc[0][1] += a0*b1; acc[0][2] += a0*b2; acc[0][3] += a0*b3;
            acc[1][0] += a1*b0; acc[1][1] += a1*b1; acc[1][2] += a1*b2; acc[1][3] += a1*b3;
            acc[2][0] += a2*b0; acc[2][1] += a2*b1; acc[2][2] += a2*b2; acc[2][3] += a2*b3;
            acc[3][0] += a3*b0; acc[3][1] += a3*b1; acc[3][2] += a3*b2; acc[3][3] += a3*b3;
        }
        __syncthreads();
    }

    #pragma unroll
    for (int i = 0; i < 4; i++) {
        #pragma unroll
        for (int j = 0; j < 4; j++) {
            const int n = bn + tn + j;
            if (n < N) {
                float v = acc[i][j];
                if (BIAS) v += bias[n];
                if (ACT == 1) v = fmaxf(v, 0.f);
                if (ACT == 2) v = (v > 20.f) ? v : log1pf(__expf(v));
                C[(size_t)(bm + tm + i) * ldc + n] = v;
            }
        }
    }
}

// ---------------------------------------------------------------------------
// fp32 -> fp16 converters (weights/state prep)
// ---------------------------------------------------------------------------
__global__ __launch_bounds__(256)
void cvt_f2h(const float* __restrict__ in, _Float16* __restrict__ out, int n4)
{
    const int g = blockIdx.x * 256 + threadIdx.x;
    if (g < n4) {
        const float4 v = reinterpret_cast<const float4*>(in)[g];
        half4 h;
        h[0] = (_Float16)v.x; h[1] = (_Float16)v.y;
        h[2] = (_Float16)v.z; h[3] = (_Float16)v.w;
        reinterpret_cast<half4*>(out)[g] = h;
    }
}

__global__ __launch_bounds__(256)
void cvtT_f2h(const float* __restrict__ in, _Float16* __restrict__ out, int R, int C)
{
    const int g = blockIdx.x * 256 + threadIdx.x;
    if (g < R * C) {
        const int r = g / C, c = g - r * C;
        out[(size_t)c * R + r] = (_Float16)in[g];
    }
}

// ---------------------------------------------------------------------------
// Causal depthwise conv (DC=4 taps) + SiLU.
// ---------------------------------------------------------------------------
__global__ __launch_bounds__(256)
void conv_silu_k(const float* __restrict__ xz, const float* __restrict__ cw,
                 const float* __restrict__ cb, float* __restrict__ xs)
{
    const int gid = blockIdx.x * 256 + threadIdx.x;
    const int d   = gid & (DI_ - 1);
    const int row = gid >> 9;
    const int t   = row & (L_ - 1);
    float acc = cb[d];
    #pragma unroll
    for (int k = 0; k < DC_; k++) {
        const int tt = t - (DC_ - 1) + k;
        if (tt >= 0)
            acc += xz[(size_t)(row - (DC_ - 1) + k) * (2 * DI_) + d] * cw[d * DC_ + k];
    }
    xs[(size_t)row * DI_ + d] = acc * (1.f / (1.f + __expf(-acc)));
}

// ---------------------------------------------------------------------------
// Scan phase 1 (B from compact xdbl32, width 32)
// ---------------------------------------------------------------------------
__global__ __launch_bounds__(512)
void scan_phase1(const float* __restrict__ dt, const float* __restrict__ xs,
                 const float* __restrict__ xdbl32, const float* __restrict__ A_log,
                 float* __restrict__ h_end, float* __restrict__ dtsum)
{
    const int c = blockIdx.x, b = blockIdx.y, d = threadIdx.x;
    __shared__ float Bs[CH][DS_];
    {
        const int tl = threadIdx.x >> 4, n = threadIdx.x & 15;
        Bs[tl][n] = xdbl32[(size_t)(b * L_ + c * CH + tl) * 32 + n];
    }
    __syncthreads();
    float Av[DS_];
    #pragma unroll
    for (int n = 0; n < DS_; n++) Av[n] = -expf(A_log[d * DS_ + n]);
    float h[DS_] = {};
    float dts = 0.f;
    const int base = b * L_ + c * CH;
    for (int tl = 0; tl < CH; tl++) {
        const float dtv = dt[(size_t)(base + tl) * DI_ + d];
        const float xv  = xs[(size_t)(base + tl) * DI_ + d];
        dts += dtv;
        const float dtx = dtv * xv;
        #pragma unroll
        for (int n = 0; n < DS_; n++)
            h[n] = __expf(dtv * Av[n]) * h[n] + dtx * Bs[tl][n];
    }
    const size_t o = (size_t)(b * NCH + c) * DI_ + d;
    #pragma unroll
    for (int n = 0; n < DS_; n++) h_end[o * DS_ + n] = h[n];
    dtsum[o] = dts;
}

// ---------------------------------------------------------------------------
// Scan phase 2
// ---------------------------------------------------------------------------
__global__ __launch_bounds__(256)
void scan_phase2(const float* __restrict__ h_end, const float* __restrict__ dtsum,
                 const float* __restrict__ A_log, float* __restrict__ h_start)
{
    const int gid = blockIdx.x * 256 + threadIdx.x;
    const int n = gid & 15;
    const int d = (gid >> 4) & (DI_ - 1);
    const int b = gid >> 13;
    const float Av = -expf(A_log[d * DS_ + n]);
    float hs = 0.f;
    for (int c = 0; c < NCH; c++) {
        const size_t o = (size_t)(b * NCH + c) * DI_ + d;
        h_start[o * DS_ + n] = hs;
        hs = __expf(Av * dtsum[o]) * hs + h_end[o * DS_ + n];
    }
}

// ---------------------------------------------------------------------------
// Scan phase 3 (B,C from compact xdbl32) -> y fp16
// ---------------------------------------------------------------------------
__global__ __launch_bounds__(512)
void scan_phase3(const float* __restrict__ dt, const float* __restrict__ xsy,
                 const float* __restrict__ xdbl32, const float* __restrict__ A_log,
                 const float* __restrict__ Dv, const float* __restrict__ xz,
                 const float* __restrict__ h_start, _Float16* __restrict__ yout)
{
    const int c = blockIdx.x, b = blockIdx.y, d = threadIdx.x;
    __shared__ float Bs[CH][DS_];
    __shared__ float Cs[CH][DS_];
    {
        const int tl = threadIdx.x >> 4, n = threadIdx.x & 15;
        const size_t r = (size_t)(b * L_ + c * CH + tl) * 32;
        Bs[tl][n] = xdbl32[r + n];
        Cs[tl][n] = xdbl32[r + 16 + n];
    }
    __syncthreads();
    float Av[DS_];
    #pragma unroll
    for (int n = 0; n < DS_; n++) Av[n] = -expf(A_log[d * DS_ + n]);
    float h[DS_];
    const size_t o = ((size_t)(b * NCH + c) * DI_ + d) * DS_;
    #pragma unroll
    for (int n = 0; n < DS_; n++) h[n] = h_start[o + n];
    const float Dd = Dv[d];
    const int base = b * L_ + c * CH;
    for (int tl = 0; tl < CH; tl++) {
        const size_t ro = (size_t)(base + tl);
        const float dtv = dt[ro * DI_ + d];
        const float xv  = xsy[ro * DI_ + d];
        const float dtx = dtv * xv;
        float acc = 0.f;
        #pragma unroll
        for (int n = 0; n < DS_; n++) {
            h[n] = __expf(dtv * Av[n]) * h[n] + dtx * Bs[tl][n];
            acc += h[n] * Cs[tl][n];
        }
        const float yv = acc + xv * Dd;
        const float zv = xz[ro * (2 * DI_) + DI_ + d];
        const float g  = zv * (1.f / (1.f + __expf(-zv)));
        yout[ro * DI_ + d] = (_Float16)(yv * g);
    }
}

// ---------------------------------------------------------------------------
// Final N=1 GEMV
// ---------------------------------------------------------------------------
__global__ __launch_bounds__(256)
void final_dot(const float* __restrict__ h2, const float* __restrict__ w3,
               const float* __restrict__ b3, float* __restrict__ out)
{
    __shared__ float w3s[128];
    const int tid = threadIdx.x;
    if (tid < 128) w3s[tid] = w3[tid];
    __syncthreads();
    const int m = blockIdx.x * 256 + tid;
    float acc = b3[0];
    #pragma unroll 4
    for (int k = 0; k < 128; k++) acc += h2[(size_t)m * 128 + k] * w3s[k];
    out[m] = acc;
}

// ---------------------------------------------------------------------------
extern "C" void kernel_launch(void* const* d_in, const int* in_sizes, int n_in,
                              void* d_out, int out_size, void* d_ws, size_t ws_size,
                              hipStream_t stream)
{
    const float* state      = (const float*)d_in[0];
    const float* in_proj_w  = (const float*)d_in[1];
    const float* conv_w     = (const float*)d_in[2];
    const float* conv_b     = (const float*)d_in[3];
    const float* x_proj_w   = (const float*)d_in[4];
    const float* dt_proj_w  = (const float*)d_in[5];
    const float* dt_proj_b  = (const float*)d_in[6];
    const float* A_log      = (const float*)d_in[7];
    const float* Dp         = (const float*)d_in[8];
    const float* out_proj_w = (const float*)d_in[9];
    const float* w1 = (const float*)d_in[10];
    const float* b1 = (const float*)d_in[11];
    const float* w2 = (const float*)d_in[12];
    const float* b2 = (const float*)d_in[13];
    const float* w3 = (const float*)d_in[14];
    const float* b3 = (const float*)d_in[15];

    float* ws      = (float*)d_ws;
    float* xz      = ws;                                   // 8,388,608 f
    float* xs      = xz     + (size_t)M_ * 2 * DI_;        // 4,194,304 f
    float* xdbl32  = xs     + (size_t)M_ * DI_;            //   262,144 f
    float* dtr32   = xdbl32 + (size_t)M_ * 32;             //   131,072 f
    float* dt      = dtr32  + (size_t)M_ * 16;             // 4,194,304 f
    float* h_end   = dt     + (size_t)M_ * DI_;            // 2,097,152 f
    float* dtsum   = h_end  + (size_t)B_ * NCH * DI_ * DS_;//   131,072 f
    float* h_start = dtsum  + (size_t)B_ * NCH * DI_;      // 2,097,152 f
    _Float16* y_h  = (_Float16*)(h_start + 2097152);       // 2,097,152 h
    _Float16* st_h = y_h + 2097152;                        // 2,097,152 h
    _Float16* wih  = st_h + 2097152;                       //   262,144 h
    _Float16* woh  = wih + 262144;                         //   131,072 h
    _Float16* w1t  = woh + 131072;                         //    65,536 h
    _Float16* w2t  = w1t + 65536;                          //    32,768 h
    // tail buffers overlay xz (z consumed by phase3 before these are written)
    _Float16* outb_h = (_Float16*)xz;                      // 2,097,152 h
    _Float16* h1_h   = (_Float16*)(xz + 1048576);          // 2,097,152 h
    float*    h2     = xz + 2097152;                       // 1,048,576 f

    // 0. fp16 prep: state + weights
    cvt_f2h<<<dim3(2048), 256, 0, stream>>>(state, st_h, M_ * DM_ / 4);
    cvt_f2h<<<dim3(256),  256, 0, stream>>>(in_proj_w, wih, 2 * DI_ * DM_ / 4);
    cvt_f2h<<<dim3(128),  256, 0, stream>>>(out_proj_w, woh, DM_ * DI_ / 4);
    cvtT_f2h<<<dim3(256), 256, 0, stream>>>(w1, w1t, 256, 256);
    cvtT_f2h<<<dim3(128), 256, 0, stream>>>(w2, w2t, 256, 128);

    // 1. xz = state @ in_proj_w^T            (M=8192, N=1024, K=256)
    hgemm_k<0, false, false><<<dim3(M_/128, 1024/64), 256, 0, stream>>>(
        st_h, DM_, wih, nullptr, xz, 2*DI_, DM_);
    // 2. causal conv + SiLU -> xs
    conv_silu_k<<<dim3(M_*DI_/256), 256, 0, stream>>>(xz, conv_w, conv_b, xs);
    // 3. x_dbl: MFMA fp16, split outputs (dtr32 / xdbl32)
    xproj_k<<<dim3(M_/64), 256, 0, stream>>>(xs, x_proj_w, dtr32, xdbl32);
    // 4. dt = softplus(dtr @ dt_proj_w^T + b)  (N=512, K=16) fp32
    gemm_k<2, true><<<dim3(M_/64, DI_/64), 256, 0, stream>>>(
        dtr32, 16, dt_proj_w, dt_proj_b, dt, DI_, DI_, DTR_);
    // 5-7. chunked selective scan
    scan_phase1<<<dim3(NCH, B_), 512, 0, stream>>>(dt, xs, xdbl32, A_log, h_end, dtsum);
    scan_phase2<<<dim3(256), 256, 0, stream>>>(h_end, dtsum, A_log, h_start);
    scan_phase3<<<dim3(NCH, B_), 512, 0, stream>>>(dt, xs, xdbl32, A_log, Dp, xz, h_start, y_h);
    // 8. out = y @ out_proj_w^T              (N=256, K=512) -> fp16
    hgemm_k<0, false, true><<<dim3(M_/128, DM_/64), 256, 0, stream>>>(
        y_h, DI_, woh, nullptr, outb_h, DM_, DI_);
    // 9. h1 = relu(out @ w1 + b1)            (N=256, K=256) -> fp16
    hgemm_k<1, true, true><<<dim3(M_/128, 256/64), 256, 0, stream>>>(
        outb_h, DM_, w1t, b1, h1_h, 256, 256);
    // 10. h2 = relu(h1 @ w2 + b2)            (N=128, K=256) -> fp32
    hgemm_k<1, true, false><<<dim3(M_/128, 128/64), 256, 0, stream>>>(
        h1_h, 256, w2t, b2, h2, 128, 256);
    // 11. out = h2 @ w3 + b3                 (N=1)
    final_dot<<<dim3(M_/256), 256, 0, stream>>>(h2, w3, b3, (float*)d_out);
}